// Round 4
// baseline (140.604 us; speedup 1.0000x reference)
//
#include <hip/hip_runtime.h>

#define NB     1024      // systems
#define NDOF   64        // dof per system
#define NSTEPS 200
#define DTF    0.002f

// ---------------- Phase 1: per-system serial chain -> cumulative 2x2 propagators
// One wave per system (lane == dof only for the seed reduction). The NHC+verlet
// per-dof map is linear: (x,v)_{n+1} = M_n (x,v)_n,
//   M_n = [[alpha, dt*sc], [-sc*c*(2-dt*c), alpha*sc^2]],  alpha = 1-dt*c.
// KE feedback uses the (validated, round-3) second-moment recursion, so the
// chain never needs per-step cross-lane traffic. We store P_n = M_n...M_1.
__global__ __launch_bounds__(256) void nhc_phase1(
    const float* __restrict__ x0, const float* __restrict__ v0,
    const float* __restrict__ kTp, const float* __restrict__ massp,
    const float* __restrict__ Qp, float4* __restrict__ P)
{
    const int tid  = blockIdx.x * blockDim.x + threadIdx.x;
    const int sys  = tid >> 6;
    const int lane = tid & 63;
    if (sys >= NB) return;

    const float kT   = kTp[0];
    const float mass = massp[0];
    const float Q    = Qp[0];

    const float dt     = DTF;
    const float dt2    = 0.5f   * DTF;
    const float dt4    = 0.25f  * DTF;
    const float dt8    = 0.125f * DTF;
    const float invQ   = 1.0f / Q;
    const float c      = dt2 / mass;          // half-kick coeff (F = -x)
    const float c2     = c * c;
    const float dtdt   = dt * dt;
    const float ndofkT = (float)NDOF * kT;
    const float alpha  = 1.0f - dt * c;       // x' x-coeff
    const float gamma  = -c * (2.0f - dt * c);// v' x-coeff (before sc factor)

    const float x = x0[sys * NDOF + lane];
    const float v = v0[sys * NDOF + lane];
    float xi0 = 0.0f, xi1 = 0.0f;

    // moment seed (wave-uniform after butterflies)
    float Sxx = x * x, Sxv = x * v, Svv = v * v;
    #pragma unroll
    for (int off = 32; off; off >>= 1) {
        Sxx += __shfl_xor(Sxx, off, 64);
        Sxv += __shfl_xor(Sxv, off, 64);
        Svv += __shfl_xor(Svv, off, 64);
    }

    float Gk = (mass * Svv - ndofkT) * invQ;  // opening G (trailing KE carried)

    // cumulative propagator P = I
    float p00 = 1.0f, p01 = 0.0f, p10 = 0.0f, p11 = 1.0f;

    for (int n = 0; n < NSTEPS; ++n) {
        // ---- first half chain (j = 1, then j = 0) ----
        xi1 = fmaf(dt4, Gk, xi1);
        float s  = __expf(-xi1 * dt8);
        float G0 = fmaf(Q * xi0, xi0, -kT) * invQ;
        xi0 = fmaf(xi0, s, dt4 * G0) * s;
        float sc  = __expf(-xi0 * dt2);
        float sc2 = sc * sc;

        // ---- moment recursion (validated round 3) ----
        Svv *= sc2;  Sxv *= sc;
        float Svv1 = fmaf(c2, Sxx, fmaf(-2.0f * c, Sxv, Svv));
        float Sxv1 = fmaf(-c, Sxx, Sxv);
        float Sxx1 = fmaf(dtdt, Svv1, fmaf(2.0f * dt, Sxv1, Sxx));
        float Sxv2 = fmaf(dt, Svv1, Sxv1);
        float Svv2 = fmaf(c2, Sxx1, fmaf(-2.0f * c, Sxv2, Svv1));
        float Sxv3 = fmaf(-c, Sxx1, Sxv2);
        Svv = Svv2 * sc2;  Sxv = Sxv3 * sc;  Sxx = Sxx1;

        // ---- second half chain ----
        float Gt = (mass * Svv - ndofkT) * invQ;
        xi0 = fmaf(xi0, s, dt4 * Gt) * s;
        float G1 = fmaf(Q * xi0, xi0, -kT) * invQ;
        xi1 = fmaf(dt4, G1, xi1);
        Gk = Gt;

        // ---- compose propagator: P = M_n * P  (off the chain's critical path)
        float b  = dt * sc;          // x' v-coeff
        float g  = gamma * sc;       // v' x-coeff
        float a2 = alpha * sc2;      // v' v-coeff
        float q00 = fmaf(alpha, p00, b * p10);
        float q01 = fmaf(alpha, p01, b * p11);
        float q10 = fmaf(g,     p00, a2 * p10);
        float q11 = fmaf(g,     p01, a2 * p11);
        p00 = q00; p01 = q01; p10 = q10; p11 = q11;

        if (lane == 0) P[sys * NSTEPS + n] = make_float4(p00, p01, p10, p11);
    }
}

// ---------------- Phase 2: embarrassingly-parallel trajectory materialization
// out[step] = P_step * (x0, v0) per dof; float4 per thread, pure streaming
// stores. x0/v0 (0.5 MB) are L2-resident; P loads broadcast across 16 lanes.
#define F4_PER_SYS (NDOF / 4)                 // 16
#define F4_PER_STEP (NB * F4_PER_SYS)         // 16384
#define TOTAL_F4 ((NSTEPS + 1) * F4_PER_STEP) // 3,293,184

__global__ __launch_bounds__(256) void nhc_phase2(
    const float* __restrict__ x0, const float* __restrict__ v0,
    const float4* __restrict__ P, float* __restrict__ out)
{
    const int t = blockIdx.x * blockDim.x + threadIdx.x;
    if (t >= TOTAL_F4) return;

    const int step = t / F4_PER_STEP;
    const int rem  = t - step * F4_PER_STEP;
    const int sys  = rem >> 4;           // /16
    const int q    = rem & 15;           // float4 index within system

    const float4 xv = *reinterpret_cast<const float4*>(&x0[sys * NDOF + q * 4]);
    const float4 vv = *reinterpret_cast<const float4*>(&v0[sys * NDOF + q * 4]);

    const size_t o = (size_t)step * (NB * NDOF) + sys * NDOF + q * 4;
    float4* __restrict__ ox = reinterpret_cast<float4*>(&out[o]);
    float4* __restrict__ ov = reinterpret_cast<float4*>(
        &out[o + (size_t)(NSTEPS + 1) * NB * NDOF]);

    if (step == 0) {
        *ox = xv;
        *ov = vv;
        return;
    }
    const float4 p = P[sys * NSTEPS + (step - 1)];
    float4 rx, rv;
    rx.x = fmaf(p.x, xv.x, p.y * vv.x);  rv.x = fmaf(p.z, xv.x, p.w * vv.x);
    rx.y = fmaf(p.x, xv.y, p.y * vv.y);  rv.y = fmaf(p.z, xv.y, p.w * vv.y);
    rx.z = fmaf(p.x, xv.z, p.y * vv.z);  rv.z = fmaf(p.z, xv.z, p.w * vv.z);
    rx.w = fmaf(p.x, xv.w, p.y * vv.w);  rv.w = fmaf(p.z, xv.w, p.w * vv.w);
    *ox = rx;
    *ov = rv;
}

// ---------------- Fallback (round-3 fused kernel) if workspace is too small
__global__ __launch_bounds__(256) void nhc_fused(
    const float* __restrict__ x0, const float* __restrict__ v0,
    const float* __restrict__ kTp, const float* __restrict__ massp,
    const float* __restrict__ Qp, float* __restrict__ out)
{
    const int tid  = blockIdx.x * blockDim.x + threadIdx.x;
    const int sys  = tid >> 6;
    const int lane = tid & 63;
    if (sys >= NB) return;

    const float kT = kTp[0], mass = massp[0], Q = Qp[0];
    const float dt = DTF, dt2 = 0.5f*DTF, dt4 = 0.25f*DTF, dt8 = 0.125f*DTF;
    const float invQ = 1.0f/Q, c = dt2/mass, c2 = c*c, dtdt = dt*dt;
    const float ndofkT = (float)NDOF * kT;

    float x = x0[sys*NDOF+lane], v = v0[sys*NDOF+lane];
    float xi0 = 0.0f, xi1 = 0.0f;
    float* __restrict__ out_x = out;
    float* __restrict__ out_v = out + (size_t)(NSTEPS+1)*NB*NDOF;
    out_x[sys*NDOF+lane] = x;  out_v[sys*NDOF+lane] = v;

    float Sxx = x*x, Sxv = x*v, Svv = v*v;
    #pragma unroll
    for (int off = 32; off; off >>= 1) {
        Sxx += __shfl_xor(Sxx, off, 64);
        Sxv += __shfl_xor(Sxv, off, 64);
        Svv += __shfl_xor(Svv, off, 64);
    }
    float Gk = (mass*Svv - ndofkT) * invQ;
    size_t widx = (size_t)NB*NDOF + sys*NDOF + lane;

    for (int n = 0; n < NSTEPS; ++n) {
        xi1 = fmaf(dt4, Gk, xi1);
        float s  = __expf(-xi1*dt8);
        float G0 = fmaf(Q*xi0, xi0, -kT) * invQ;
        xi0 = fmaf(xi0, s, dt4*G0) * s;
        float sc = __expf(-xi0*dt2), sc2 = sc*sc;
        v *= sc;  v = fmaf(-c,x,v);  x = fmaf(dt,v,x);  v = fmaf(-c,x,v);  v *= sc;
        Svv *= sc2;  Sxv *= sc;
        float Svv1 = fmaf(c2,Sxx,fmaf(-2.0f*c,Sxv,Svv));
        float Sxv1 = fmaf(-c,Sxx,Sxv);
        float Sxx1 = fmaf(dtdt,Svv1,fmaf(2.0f*dt,Sxv1,Sxx));
        float Sxv2 = fmaf(dt,Svv1,Sxv1);
        float Svv2 = fmaf(c2,Sxx1,fmaf(-2.0f*c,Sxv2,Svv1));
        float Sxv3 = fmaf(-c,Sxx1,Sxv2);
        Svv = Svv2*sc2;  Sxv = Sxv3*sc;  Sxx = Sxx1;
        float Gt = (mass*Svv - ndofkT) * invQ;
        xi0 = fmaf(xi0, s, dt4*Gt) * s;
        float G1 = fmaf(Q*xi0, xi0, -kT) * invQ;
        xi1 = fmaf(dt4, G1, xi1);
        Gk = Gt;
        out_x[widx] = x;  out_v[widx] = v;
        widx += (size_t)NB*NDOF;
    }
}

extern "C" void kernel_launch(void* const* d_in, const int* in_sizes, int n_in,
                              void* d_out, int out_size, void* d_ws, size_t ws_size,
                              hipStream_t stream) {
    const float* x0   = (const float*)d_in[0];
    const float* v0   = (const float*)d_in[1];
    const float* kT   = (const float*)d_in[2];
    const float* mass = (const float*)d_in[3];
    const float* Q    = (const float*)d_in[4];
    float* out = (float*)d_out;

    const size_t ws_needed = (size_t)NB * NSTEPS * 4 * sizeof(float); // 3.28 MB
    if (ws_size < ws_needed) {
        nhc_fused<<<NB * NDOF / 256, 256, 0, stream>>>(x0, v0, kT, mass, Q, out);
        return;
    }
    float4* P = (float4*)d_ws;

    nhc_phase1<<<NB * NDOF / 256, 256, 0, stream>>>(x0, v0, kT, mass, Q, P);

    const int blocks = (TOTAL_F4 + 255) / 256;   // 12864
    nhc_phase2<<<blocks, 256, 0, stream>>>(x0, v0, P, out);
}

// Round 5
// 122.163 us; speedup vs baseline: 1.1510x; 1.1510x over previous
//
#include <hip/hip_runtime.h>

#define NB     1024      // systems
#define NDOF   64        // dof per system
#define NSTEPS 200
#define DTF    0.002f

// One wave (64 lanes) per system; lane == dof. Fused single kernel:
// trajectory stores are hidden under the serial thermostat chain (round-3/4
// evidence). The chain is algebraically flattened to ~15 dependent fma/step:
//  - exp() replaced by 2nd-order Taylor (|z|<~3e-4 -> rel err ~1e-10)
//  - u = sc^2 computed by its own Taylor, parallel to sc
//  - the 7-stage moment recursion collapsed to Gt = u*(P1 + sc*P2 + u*P3) - C
//    with P1..P3 = const * prev moments, precomputed OFF the critical path
//  - xi1's step-end and next-step-opening increments folded into one fma
__global__ __launch_bounds__(256) void nhc_kernel(
    const float* __restrict__ x0, const float* __restrict__ v0,
    const float* __restrict__ kTp, const float* __restrict__ massp,
    const float* __restrict__ Qp, float* __restrict__ out)
{
    const int tid  = blockIdx.x * blockDim.x + threadIdx.x;
    const int sys  = tid >> 6;
    const int lane = tid & 63;
    if (sys >= NB) return;

    const float kT   = kTp[0];
    const float mass = massp[0];
    const float Q    = Qp[0];

    const float dt   = DTF;
    const float dt2  = 0.5f   * DTF;
    const float dt4  = 0.25f  * DTF;
    const float dt8  = 0.125f * DTF;
    const float invQ = 1.0f / Q;
    const float mi   = mass * invQ;
    const float c    = dt2 / mass;            // half-kick coeff (F = -x)
    const float alpha = 1.0f - dt * c;

    // Svv2 = K1*Sxx + K2*(sc*Sxv) + K3*(u*Svv)   (closed form of the 2-kick map)
    const float K1 = c * c * (alpha + 1.0f) * (alpha + 1.0f);
    const float K2 = 2.0f * dt * c * c * (alpha + 2.0f) - 4.0f * c;
    const float K3 = alpha * alpha;
    // Sxx1 = A1*Sxx + A2*(sc*Sxv) + A3*(u*Svv)
    const float A1 = alpha * alpha, A2 = 2.0f * dt * alpha, A3 = dt * dt;
    // Sxv3 = L1*Sxx + L2*(sc*Sxv) + L3*(u*Svv)
    const float L1 = -c * alpha * (alpha + 1.0f);
    const float L2 = 1.0f - 2.0f * dt * c * (alpha + 1.0f);
    const float L3 = dt * alpha;
    // Taylor coeffs: exp(z) ~ 1 + z + z^2/2, z = -k*xi  ->  fmaf(xi, fmaf(A,xi,B), 1)
    const float Bs = -dt8, As = 0.5f * dt8 * dt8;   // s  = exp(-xi1*dt/8)
    const float Bc = -dt2, Ac = 0.5f * dt2 * dt2;   // sc = exp(-xi0*dt/2)
    const float Bu = -dt,  Au = 0.5f * dt * dt;     // u  = exp(-xi0*dt) = sc^2
    const float negC   = -(float)NDOF * kT * invQ;  // -ndof*kT/Q
    const float negkTQ = -kT * invQ;

    float x = x0[sys * NDOF + lane];
    float v = v0[sys * NDOF + lane];

    float* __restrict__ out_x = out;
    float* __restrict__ out_v = out + (size_t)(NSTEPS + 1) * NB * NDOF;

    // step-0 snapshot
    out_x[sys * NDOF + lane] = x;
    out_v[sys * NDOF + lane] = v;

    // one-time moment seed (wave-uniform after butterflies), pre-scaled by mi
    float sxx = x * x, sxv = x * v, svv = v * v;
    #pragma unroll
    for (int off = 32; off; off >>= 1) {
        sxx += __shfl_xor(sxx, off, 64);
        sxv += __shfl_xor(sxv, off, 64);
        svv += __shfl_xor(svv, off, 64);
    }
    float Sxx = mi * sxx, Sxv = mi * sxv, Svv = mi * svv;
    float P1 = K1 * Sxx, P2 = K2 * Sxv, P3 = K3 * Svv;

    float xi0 = 0.0f;
    float xi1 = dt4 * (Svv + negC);     // opening increment pre-folded (G_a)
    float t0  = dt4 * negkTQ;           // dt4*G0 for first iteration (xi0=0)

    size_t widx = (size_t)NB * NDOF + sys * NDOF + lane;  // step-1 slot

    for (int n = 0; n < NSTEPS; ++n) {
        // ---- critical scalar chain (~15 dependent fma) ----
        float s  = fmaf(xi1, fmaf(As, xi1, Bs), 1.0f);     // exp(-xi1*dt/8)
        xi0 = fmaf(xi0, s, t0) * s;                        // first-half xi0
        float sc = fmaf(xi0, fmaf(Ac, xi0, Bc), 1.0f);     // exp(-xi0*dt/2)
        float u  = fmaf(xi0, fmaf(Au, xi0, Bu), 1.0f);     // exp(-xi0*dt) = sc^2
        float b  = fmaf(u, P3, fmaf(sc, P2, P1));          // mi*Svv2
        float Gt = fmaf(u, b, negC);                       // trailing-KE G
        float t  = dt4 * Gt;
        xi0 = fmaf(xi0, s, t) * s;                         // second-half xi0
        float G1 = fmaf(xi0, xi0, negkTQ);                 // (Q*xi0^2-kT)/Q
        xi1 = xi1 + fmaf(dt4, G1, t);                      // step-end + next-open
        t0  = dt4 * G1;                                    // next step's dt4*G0

        // ---- off-critical: moment state + P precompute for next step ----
        float X = sc * Sxv, V = u * Svv;
        float Sxx1 = fmaf(A1, Sxx, fmaf(A2, X, A3 * V));
        Sxv = sc * fmaf(L1, Sxx, fmaf(L2, X, L3 * V));
        Svv = u * b;                                       // mi*Svv'
        Sxx = Sxx1;
        P1 = K1 * Sxx; P2 = K2 * Sxv; P3 = K3 * Svv;

        // ---- off-critical: per-dof trajectory + stores (hidden in stalls) ----
        v *= sc;
        v = fmaf(-c, x, v);
        x = fmaf(dt, v, x);
        v = fmaf(-c, x, v);
        v *= sc;

        out_x[widx] = x;
        out_v[widx] = v;
        widx += (size_t)NB * NDOF;
    }
}

extern "C" void kernel_launch(void* const* d_in, const int* in_sizes, int n_in,
                              void* d_out, int out_size, void* d_ws, size_t ws_size,
                              hipStream_t stream) {
    const float* x0   = (const float*)d_in[0];
    const float* v0   = (const float*)d_in[1];
    const float* kT   = (const float*)d_in[2];
    const float* mass = (const float*)d_in[3];
    const float* Q    = (const float*)d_in[4];
    float* out = (float*)d_out;

    const int total = NB * NDOF;           // 65536 threads
    const int block = 256;
    const int grid  = total / block;       // 256 blocks, 1 block/CU
    nhc_kernel<<<grid, block, 0, stream>>>(x0, v0, kT, mass, Q, out);
}